// Round 5
// baseline (238.466 us; speedup 1.0000x reference)
//
#include <hip/hip_runtime.h>
#include <math.h>

#define T_TOKENS 16384
#define D_DIM    2048
#define E_EXP    64
#define TOPK     8

// ---------------- Kernel 1: partial logits GEMM ----------------
// grid (T/128, ns), 128 threads (2 waves). Block tile 128 tok x 64 exp,
// THREAD TILE 8x8 -> 64 B LDS-read per 64 FMA = 1 B/FMA (R4 was 2 B/FMA;
// LDS return path at 85 B/cyc/CU [m134] was the bound).
// xl[k][pos(t)] with swizzle pos(t)=t+4*(t>>6): the 16 per-wave x-fragment
// addresses spread over all 8 bank-groups 2-way (free, m136).
// gl[k][e]: 4 distinct addrs/wave, 16-fold broadcast -> conflict-free.

#define TT   128                // tokens per block
#define KC   32                 // k chunk
#define XT   132                // xl row stride (128 + 1 swizzle chunk), 16B-aligned
#define GT   68                 // gl row stride, 16B-aligned

__global__ __launch_bounds__(128, 2) void moe_logits_kernel(
    const float* __restrict__ x, const float* __restrict__ gw,
    float* __restrict__ part, float* __restrict__ counts_zero, int ns)
{
  __shared__ float xl[KC * XT];   // 16896 B
  __shared__ float gl[KC * GT];   // 8704 B

  const int tid  = threadIdx.x;
  const int tg   = tid & 15;      // token group: tokens tg*8..tg*8+7
  const int eg   = tid >> 4;      // expert group: experts eg*8..eg*8+7
  const int ks   = blockIdx.y;
  const int tok0 = blockIdx.x * TT;
  const int ksz  = D_DIM / ns;
  const int k0   = ks * ksz;
  const int nchunk = ksz / KC;

  if (blockIdx.x == 0 && ks == 0 && tid < E_EXP) counts_zero[tid] = 0.0f;

  const int xbase = tg * 8 + 4 * (tg >> 3);   // swizzled fragment base in xl row

  float4 acc[16];                 // [token j][expert half h] -> acc[j*2+h]
  #pragma unroll
  for (int j = 0; j < 16; ++j) acc[j] = make_float4(0.f, 0.f, 0.f, 0.f);

  #pragma unroll 1
  for (int c = 0; c < nchunk; ++c) {
    const int kc0 = k0 + c * KC;

    // ---- stage x[128 tok][32 k] -> xl[k][pos(t)] (8 float4 / thread) ----
    #pragma unroll
    for (int p = 0; p < 8; ++p) {
      const int flat = p * 128 + tid;
      const int row  = flat >> 3;           // token 0..127
      const int c4   = flat & 7;            // float4 col in 32-k row
      float4 v = *(const float4*)&x[(size_t)(tok0 + row) * D_DIM + kc0 + c4 * 4];
      const int pos = row + 4 * (row >> 6); // swizzle
      xl[(c4 * 4 + 0) * XT + pos] = v.x;
      xl[(c4 * 4 + 1) * XT + pos] = v.y;
      xl[(c4 * 4 + 2) * XT + pos] = v.z;
      xl[(c4 * 4 + 3) * XT + pos] = v.w;
    }
    // ---- stage gw[64 e][32 k] -> gl[k][e] (4 float4 / thread) ----
    #pragma unroll
    for (int p = 0; p < 4; ++p) {
      const int flat = p * 128 + tid;
      const int erow = flat >> 3;           // expert 0..63
      const int c4   = flat & 7;
      float4 v = *(const float4*)&gw[(size_t)erow * D_DIM + kc0 + c4 * 4];
      gl[(c4 * 4 + 0) * GT + erow] = v.x;
      gl[(c4 * 4 + 1) * GT + erow] = v.y;
      gl[(c4 * 4 + 2) * GT + erow] = v.z;
      gl[(c4 * 4 + 3) * GT + erow] = v.w;
    }
    __syncthreads();

    // ---- compute: 32 k-steps of 8x8 outer product ----
    #pragma unroll
    for (int k = 0; k < KC; ++k) {
      float4 xv0 = *(const float4*)&xl[k * XT + xbase];
      float4 xv1 = *(const float4*)&xl[k * XT + xbase + 4];
      float4 gv0 = *(const float4*)&gl[k * GT + eg * 8];
      float4 gv1 = *(const float4*)&gl[k * GT + eg * 8 + 4];
      const float xs[8] = {xv0.x, xv0.y, xv0.z, xv0.w, xv1.x, xv1.y, xv1.z, xv1.w};
      #pragma unroll
      for (int j = 0; j < 8; ++j) {
        const float xj = xs[j];
        acc[j*2+0].x = fmaf(xj, gv0.x, acc[j*2+0].x);
        acc[j*2+0].y = fmaf(xj, gv0.y, acc[j*2+0].y);
        acc[j*2+0].z = fmaf(xj, gv0.z, acc[j*2+0].z);
        acc[j*2+0].w = fmaf(xj, gv0.w, acc[j*2+0].w);
        acc[j*2+1].x = fmaf(xj, gv1.x, acc[j*2+1].x);
        acc[j*2+1].y = fmaf(xj, gv1.y, acc[j*2+1].y);
        acc[j*2+1].z = fmaf(xj, gv1.z, acc[j*2+1].z);
        acc[j*2+1].w = fmaf(xj, gv1.w, acc[j*2+1].w);
      }
    }
    __syncthreads();
  }

  // ---- store partials part[ks][tok][e] ----
  #pragma unroll
  for (int j = 0; j < 8; ++j) {
    const size_t t = (size_t)tok0 + tg * 8 + j;
    float* pp = &part[((size_t)ks * T_TOKENS + t) * E_EXP + eg * 8];
    *(float4*)&pp[0] = acc[j*2+0];
    *(float4*)&pp[4] = acc[j*2+1];
  }
}

// ---------------- Kernel 2: reduce + bias, top-8, softmax, counts ----------------
// 256 blocks x 64 threads (thread-per-token) -> all 256 CUs participate.
__global__ __launch_bounds__(64) void topk_kernel(
    const float* __restrict__ part, const float* __restrict__ bias,
    float* __restrict__ out, int ns)
{
  __shared__ unsigned hist[E_EXP];
  const int tid = threadIdx.x;            // 0..63
  const int t = blockIdx.x * 64 + tid;
  hist[tid] = 0;
  __syncthreads();

  float l[E_EXP];
  #pragma unroll
  for (int j = 0; j < E_EXP / 4; ++j) {
    float4 b = *(const float4*)&bias[j * 4];
    l[4*j] = b.x; l[4*j+1] = b.y; l[4*j+2] = b.z; l[4*j+3] = b.w;
  }
  for (int ks = 0; ks < ns; ++ks) {
    const float4* p = (const float4*)&part[((size_t)ks * T_TOKENS + t) * E_EXP];
    #pragma unroll
    for (int j = 0; j < E_EXP / 4; ++j) {
      float4 v = p[j];
      l[4*j] += v.x; l[4*j+1] += v.y; l[4*j+2] += v.z; l[4*j+3] += v.w;
    }
  }

  float tv[TOPK]; int tix[TOPK];
  unsigned long long used = 0ull;
  #pragma unroll
  for (int k = 0; k < TOPK; ++k) {
    float best = -INFINITY; int bi = 0;
    #pragma unroll
    for (int j = 0; j < E_EXP; ++j) {
      bool ok = (((used >> j) & 1ull) == 0ull) && (l[j] > best);  // strict >: lowest index wins ties
      best = ok ? l[j] : best;
      bi   = ok ? j : bi;
    }
    tv[k] = best; tix[k] = bi;
    used |= (1ull << bi);
  }

  float m = tv[0], s = 0.0f, w[TOPK];
  #pragma unroll
  for (int k = 0; k < TOPK; ++k) { w[k] = expf(tv[k] - m); s += w[k]; }
  float inv = 1.0f / s;

  #pragma unroll
  for (int k = 0; k < TOPK; ++k) {
    out[(size_t)t * TOPK + k] = (float)tix[k];                        // indices as fp32
    out[(size_t)T_TOKENS * TOPK + (size_t)t * TOPK + k] = w[k] * inv; // weights
  }

  #pragma unroll
  for (int k = 0; k < TOPK; ++k) atomicAdd(&hist[tix[k]], 1u);
  __syncthreads();
  atomicAdd(&out[2 * (size_t)T_TOKENS * TOPK + tid], (float)hist[tid]);
}

extern "C" void kernel_launch(void* const* d_in, const int* in_sizes, int n_in,
                              void* d_out, int out_size, void* d_ws, size_t ws_size,
                              hipStream_t stream) {
  const float* x    = (const float*)d_in[0];
  const float* gw   = (const float*)d_in[1];
  const float* bias = (const float*)d_in[2];
  float* out  = (float*)d_out;
  float* part = (float*)d_ws;

  const size_t slice_bytes = (size_t)T_TOKENS * E_EXP * sizeof(float);  // 4 MB
  int ns = 1;
  if (ws_size >= 8 * slice_bytes)      ns = 8;   // 32 MB scratch
  else if (ws_size >= 4 * slice_bytes) ns = 4;
  else if (ws_size >= 2 * slice_bytes) ns = 2;

  moe_logits_kernel<<<dim3(T_TOKENS / TT, ns), dim3(128), 0, stream>>>(
      x, gw, part, out + 2 * (size_t)T_TOKENS * TOPK, ns);
  topk_kernel<<<dim3(T_TOKENS / 64), dim3(64), 0, stream>>>(part, bias, out, ns);
}

// Round 6
// 233.820 us; speedup vs baseline: 1.0199x; 1.0199x over previous
//
#include <hip/hip_runtime.h>
#include <math.h>

#define T_TOKENS 16384
#define D_DIM    2048
#define E_EXP    64
#define TOPK     8
#define NS       8              // split-K slices

typedef __attribute__((ext_vector_type(8))) short bf16x8;
typedef __attribute__((ext_vector_type(4))) float f32x4;

__device__ __forceinline__ unsigned short bf16rne(float f) {
  unsigned u = __builtin_bit_cast(unsigned, f);
  unsigned r = u + 0x7fffu + ((u >> 16) & 1u);
  return (unsigned short)(r >> 16);
}
__device__ __forceinline__ float bf16f(unsigned short h) {
  return __builtin_bit_cast(float, (unsigned)h << 16);
}

// ---------------- Kernel 0: pre-convert gate_w to frag-ordered bf16 hi/lo ----
// Packed layout: entry id = ((c*4 + kq)*64 + e), c = k/32 chunk, kq = k-quad,
// e = expert. Entry = 8 bf16 (16 B) = g[e][c*32 + kq*8 .. +7].
// Also zeroes the counts output region (harness poisons d_out each launch).
__global__ __launch_bounds__(256) void convert_g_kernel(
    const float* __restrict__ gw, unsigned short* __restrict__ ph,
    unsigned short* __restrict__ pl, float* __restrict__ counts_zero)
{
  const int id = blockIdx.x * 256 + threadIdx.x;   // 0..16383
  if (blockIdx.x == 0 && threadIdx.x < E_EXP) counts_zero[threadIdx.x] = 0.0f;

  const int e  = id & 63;
  const int kq = (id >> 6) & 3;
  const int c  = id >> 8;
  const float* gp = &gw[(size_t)e * D_DIM + c * 32 + kq * 8];
  float4 v0 = *(const float4*)&gp[0];
  float4 v1 = *(const float4*)&gp[4];
  const float xs[8] = {v0.x, v0.y, v0.z, v0.w, v1.x, v1.y, v1.z, v1.w};
  unsigned short h[8], l[8];
  #pragma unroll
  for (int j = 0; j < 8; ++j) {
    h[j] = bf16rne(xs[j]);
    l[j] = bf16rne(xs[j] - bf16f(h[j]));
  }
  // 16 B vector writes, consecutive id -> consecutive 16 B: coalesced
  *(short4*)&ph[(size_t)id * 8 + 0] = make_short4(h[0], h[1], h[2], h[3]);
  *(short4*)&ph[(size_t)id * 8 + 4] = make_short4(h[4], h[5], h[6], h[7]);
  *(short4*)&pl[(size_t)id * 8 + 0] = make_short4(l[0], l[1], l[2], l[3]);
  *(short4*)&pl[(size_t)id * 8 + 4] = make_short4(l[4], l[5], l[6], l[7]);
}

// ---------------- Kernel 1: partial logits via split-bf16 MFMA ----------------
// grid (T/128, NS), 256 thr = 4 waves, NO LDS / NO barriers.
// Wave tile: 32 tok x 64 exp. Per 32-k chunk:
//   A-frags: x[t = base + sub*16 + (lane&15)][kc + (lane>>4)*8 + j] (fp32,
//            2 x b128 global, 64B/row segments) -> split to ah/al bf16.
//   B-frags: packed ph/pl, 16-lane-contiguous 256 B segments (L2-resident).
//   12 MFMA per sub-chunk: acc += ah*bh + ah*bl + al*bh  (xl*gl ~2^-18 dropped).
// Verified layouts (m89/m118): A[m=lane&15][k=quad*8+j]; B[n=lane&15][k=quad*8+j];
// D: row(m)=quad*4+reg, col(n)=lane&15.
__global__ __launch_bounds__(256, 4) void moe_logits_kernel(
    const float* __restrict__ x, const unsigned short* __restrict__ ph,
    const unsigned short* __restrict__ pl, float* __restrict__ part)
{
  const int tid  = threadIdx.x;
  const int wave = tid >> 6;
  const int lane = tid & 63;
  const int l15  = lane & 15;
  const int quad = lane >> 4;
  const int ks   = blockIdx.y;
  const int ksz  = D_DIM / NS;                    // 256
  const int k0   = ks * ksz;
  const int tokw = blockIdx.x * 128 + wave * 32;  // wave's 32 tokens

  f32x4 acc[2][4];
  #pragma unroll
  for (int s = 0; s < 2; ++s)
    #pragma unroll
    for (int et = 0; et < 4; ++et) acc[s][et] = (f32x4){0.f, 0.f, 0.f, 0.f};

  #pragma unroll 1
  for (int c8 = 0; c8 < ksz / 32; ++c8) {
    const int kc = k0 + c8 * 32;
    const int cg = kc >> 5;                       // global 32-k chunk index

    // ---- B fragments: 4 expert tiles x {hi,lo} ----
    bf16x8 bh[4], bl[4];
    const size_t bbase = (((size_t)cg * 4 + quad) * 64 + l15) * 8;
    #pragma unroll
    for (int et = 0; et < 4; ++et) {
      bh[et] = *(const bf16x8*)&ph[bbase + (size_t)et * 16 * 8];
      bl[et] = *(const bf16x8*)&pl[bbase + (size_t)et * 16 * 8];
    }

    // ---- 2 token sub-tiles ----
    #pragma unroll
    for (int sub = 0; sub < 2; ++sub) {
      const int t = tokw + sub * 16 + l15;
      const float* xp = &x[(size_t)t * D_DIM + kc + quad * 8];
      float4 v0 = *(const float4*)&xp[0];
      float4 v1 = *(const float4*)&xp[4];
      const float xs[8] = {v0.x, v0.y, v0.z, v0.w, v1.x, v1.y, v1.z, v1.w};
      bf16x8 ah, al;
      #pragma unroll
      for (int j = 0; j < 8; ++j) {
        unsigned short h = bf16rne(xs[j]);
        ah[j] = (short)h;
        al[j] = (short)bf16rne(xs[j] - bf16f(h));
      }
      #pragma unroll
      for (int et = 0; et < 4; ++et) {
        acc[sub][et] = __builtin_amdgcn_mfma_f32_16x16x32_bf16(ah, bh[et], acc[sub][et], 0, 0, 0);
        acc[sub][et] = __builtin_amdgcn_mfma_f32_16x16x32_bf16(ah, bl[et], acc[sub][et], 0, 0, 0);
        acc[sub][et] = __builtin_amdgcn_mfma_f32_16x16x32_bf16(al, bh[et], acc[sub][et], 0, 0, 0);
      }
    }
  }

  // ---- store partials: D row = quad*4 + r (token), col = l15 (expert) ----
  #pragma unroll
  for (int sub = 0; sub < 2; ++sub) {
    #pragma unroll
    for (int et = 0; et < 4; ++et) {
      #pragma unroll
      for (int r = 0; r < 4; ++r) {
        const size_t t = (size_t)tokw + sub * 16 + quad * 4 + r;
        part[((size_t)ks * T_TOKENS + t) * E_EXP + et * 16 + l15] = acc[sub][et][r];
      }
    }
  }
}

// ---------------- Kernel 2: reduce + bias, top-8, softmax, counts ----------------
// 256 blocks x 64 threads (thread-per-token).
__global__ __launch_bounds__(64) void topk_kernel(
    const float* __restrict__ part, const float* __restrict__ bias,
    float* __restrict__ out)
{
  __shared__ unsigned hist[E_EXP];
  const int tid = threadIdx.x;            // 0..63
  const int t = blockIdx.x * 64 + tid;
  hist[tid] = 0;
  __syncthreads();

  float l[E_EXP];
  #pragma unroll
  for (int j = 0; j < E_EXP / 4; ++j) {
    float4 b = *(const float4*)&bias[j * 4];
    l[4*j] = b.x; l[4*j+1] = b.y; l[4*j+2] = b.z; l[4*j+3] = b.w;
  }
  #pragma unroll 1
  for (int ks = 0; ks < NS; ++ks) {
    const float4* p = (const float4*)&part[((size_t)ks * T_TOKENS + t) * E_EXP];
    #pragma unroll
    for (int j = 0; j < E_EXP / 4; ++j) {
      float4 v = p[j];
      l[4*j] += v.x; l[4*j+1] += v.y; l[4*j+2] += v.z; l[4*j+3] += v.w;
    }
  }

  float tv[TOPK]; int tix[TOPK];
  unsigned long long used = 0ull;
  #pragma unroll
  for (int k = 0; k < TOPK; ++k) {
    float best = -INFINITY; int bi = 0;
    #pragma unroll
    for (int j = 0; j < E_EXP; ++j) {
      bool ok = (((used >> j) & 1ull) == 0ull) && (l[j] > best);  // strict >: lowest index wins ties
      best = ok ? l[j] : best;
      bi   = ok ? j : bi;
    }
    tv[k] = best; tix[k] = bi;
    used |= (1ull << bi);
  }

  float m = tv[0], s = 0.0f, w[TOPK];
  #pragma unroll
  for (int k = 0; k < TOPK; ++k) { w[k] = expf(tv[k] - m); s += w[k]; }
  float inv = 1.0f / s;

  #pragma unroll
  for (int k = 0; k < TOPK; ++k) {
    out[(size_t)t * TOPK + k] = (float)tix[k];                        // indices as fp32
    out[(size_t)T_TOKENS * TOPK + (size_t)t * TOPK + k] = w[k] * inv; // weights
  }

  #pragma unroll
  for (int k = 0; k < TOPK; ++k) atomicAdd(&hist[tix[k]], 1u);
  __syncthreads();
  atomicAdd(&out[2 * (size_t)T_TOKENS * TOPK + tid], (float)hist[tid]);
}

extern "C" void kernel_launch(void* const* d_in, const int* in_sizes, int n_in,
                              void* d_out, int out_size, void* d_ws, size_t ws_size,
                              hipStream_t stream) {
  const float* x    = (const float*)d_in[0];
  const float* gw   = (const float*)d_in[1];
  const float* bias = (const float*)d_in[2];
  float* out  = (float*)d_out;

  // ws layout: part (NS*4 MB) | ph (256 KB) | pl (256 KB)
  float* part = (float*)d_ws;
  const size_t part_elems = (size_t)NS * T_TOKENS * E_EXP;
  unsigned short* ph = (unsigned short*)((char*)d_ws + part_elems * sizeof(float));
  unsigned short* pl = ph + (size_t)E_EXP * D_DIM;

  convert_g_kernel<<<dim3(E_EXP * D_DIM / 8 / 256), dim3(256), 0, stream>>>(
      gw, ph, pl, out + 2 * (size_t)T_TOKENS * TOPK);
  moe_logits_kernel<<<dim3(T_TOKENS / 128, NS), dim3(256), 0, stream>>>(
      x, ph, pl, part);
  topk_kernel<<<dim3(T_TOKENS / 64), dim3(64), 0, stream>>>(part, bias, out);
}